// Round 11
// baseline (30.091 us; speedup 1.0000x reference)
//
#include <hip/hip_runtime.h>
#include <math.h>

// HungarianMatcher cost matrix:
//   C[i,j] = 5*L1(pred_box_i, tgt_box_j) + 2*focal(tgt class j) - 2*GIoU
// Shapes: pred_logits [BN,NC], pred_boxes [BN,4], tgt_ids [NT], tgt_bbox [NT,4]
// BN=16*900=14400, NC=91, NT=960. Output [BN,NT] fp32.
//
// R10: two-kernel split. K1 streams all BN*NC focal-table entries to d_ws
// (removes the cold-load + transcendental chain from K2's per-block critical
// path). K2 is barrier-free, LDS-free, trans-free: early-issued global
// gathers for class costs (L2-hot, one 364B row per block), pure VALU body,
// nontemporal float4 stores. Falls back to the proven R9b single kernel if
// ws is too small, then to a generic kernel for odd shapes.

#define ALPHA_F   0.25f
#define COST_CLS  2.0f
#define COST_BBOX 5.0f
#define COST_GIOU 2.0f
#define EPS_F     1e-8f

constexpr int THREADS = 256;

typedef float vfloat4 __attribute__((ext_vector_type(4)));

__device__ __forceinline__ float focal_entry(float x) {
    const float p  = 1.0f / (1.0f + __expf(-x));
    const float om = 1.0f - p;
    const float neg = (1.0f - ALPHA_F) * p * p * (-__logf(om + EPS_F));
    const float pos = ALPHA_F * om * om        * (-__logf(p  + EPS_F));
    return COST_CLS * (pos - neg) + COST_GIOU;   // GIoU "+2" folded in
}

// ---------------- K1: focal table for all rows -> ws[row*NCP + c] ----------
template<int NC, int NCP>
__global__ __launch_bounds__(THREADS) void focal_table_kernel(
    const float* __restrict__ logits,   // [BN, NC]
    float*       __restrict__ tab,      // [BN, NCP]
    int total)                          // BN * NC
{
    const int idx = blockIdx.x * THREADS + threadIdx.x;
    if (idx >= total) return;
    const int row = idx / NC;
    const int c   = idx - row * NC;
    const float x = __builtin_nontemporal_load(logits + idx);
    tab[(size_t)row * NCP + c] = focal_entry(x);
}

// ---------------- K2: cost matrix, barrier/LDS/trans-free ------------------
template<int NC, int NT>
__global__ __launch_bounds__(THREADS) void matcher_k2(
    const float* __restrict__ tab,      // [BN, 96] folded class costs
    const float* __restrict__ boxes,    // [BN, 4] cxcywh
    const int*   __restrict__ tids,     // [NT]
    const float* __restrict__ tboxes,   // [NT, 4] cxcywh
    float*       __restrict__ out)      // [BN, NT]
{
    constexpr int ROWS = 2;
    constexpr int JPT  = 4;                   // contiguous targets per thread
    constexpr int NJT  = NT / JPT;            // 240 active threads
    constexpr int NCP  = 96;

    const int tid  = threadIdx.x;
    const int row0 = blockIdx.x * ROWS;
    if (tid >= NJT) return;                   // no barrier anywhere -> safe

    // ---- class ids, then early-issued table gathers (both rows) ----
    const int4 tv = reinterpret_cast<const int4*>(tids)[tid];
    const int ic[JPT] = {tv.x, tv.y, tv.z, tv.w};
    const float* __restrict__ t0 = tab + (size_t)row0 * NCP;
    const float* __restrict__ t1 = t0 + NCP;
    float cc0[JPT], cc1[JPT];
    #pragma unroll
    for (int k = 0; k < JPT; ++k) { cc0[k] = t0[ic[k]]; cc1[k] = t1[ic[k]]; }

    // ---- target boxes (raw cxcywh) ----
    float4 tb[JPT];
    #pragma unroll
    for (int k = 0; k < JPT; ++k)
        tb[k] = reinterpret_cast<const float4*>(tboxes)[tid * JPT + k];

    float* __restrict__ optr = out + (size_t)row0 * NT + tid * JPT;
    #pragma unroll
    for (int r = 0; r < ROWS; ++r) {
        // block-uniform pred box (scalar-load path)
        const float4 pb = reinterpret_cast<const float4*>(boxes)[row0 + r];
        const float px0 = pb.x - 0.5f * pb.z, py0 = pb.y - 0.5f * pb.w;
        const float px1 = pb.x + 0.5f * pb.z, py1 = pb.y + 0.5f * pb.w;
        const float parea = pb.z * pb.w;

        float rv[JPT];
        #pragma unroll
        for (int k = 0; k < JPT; ++k) {
            const float4 t = tb[k];
            const float hw = 0.5f * t.z, hh = 0.5f * t.w;
            const float tx0 = t.x - hw, tx1 = t.x + hw;
            const float ty0 = t.y - hh, ty1 = t.y + hh;
            const float tarea = t.z * t.w;
            // L1 in cxcywh space (abs folds into VOP3 src modifiers)
            const float l1 = (fabsf(pb.x - t.x) + fabsf(pb.y - t.y))
                           + (fabsf(pb.z - t.z) + fabsf(pb.w - t.w));
            // raw intersection extents (feed enclosing box too)
            const float iwr = fminf(px1, tx1) - fmaxf(px0, tx0);
            const float ihr = fminf(py1, ty1) - fmaxf(py0, ty0);
            const float inter = fmaxf(iwr, 0.0f) * fmaxf(ihr, 0.0f);
            const float uni = (parea + tarea) - inter;
            // enclosing box via identity: cw = pw + tw - iwr
            const float cw = (pb.z + t.z) - iwr;
            const float ch = (pb.w + t.w) - ihr;
            const float carea = cw * ch;
            // C = 5*l1 + tbl[c] - 2*(inter*carea + uni^2)/(uni*carea)
            const float num  = fmaf(inter, carea, uni * uni);
            const float rcpd = __builtin_amdgcn_rcpf(uni * carea);
            const float ctab = (r == 0) ? cc0[k] : cc1[k];
            const float base = fmaf(COST_BBOX, l1, ctab);
            rv[k] = fmaf(-2.0f * num, rcpd, base);
        }
        vfloat4 v;
        v.x = rv[0]; v.y = rv[1]; v.z = rv[2]; v.w = rv[3];
        __builtin_nontemporal_store(v, reinterpret_cast<vfloat4*>(optr));
        optr += NT;
    }
}

// ---------------- fallback: proven R9b single kernel (ROWS = 2) ------------
template<int NC, int NT>
__global__ __launch_bounds__(THREADS) void matcher_kernel_s(
    const float* __restrict__ logits, const float* __restrict__ boxes,
    const int* __restrict__ tids, const float* __restrict__ tboxes,
    float* __restrict__ out)
{
    constexpr int ROWS = 2;
    constexpr int JPT  = 4;
    constexpr int NJT  = NT / JPT;
    constexpr int NTAB = ROWS * NC;
    constexpr int CSTR = 3;

    __shared__ float s_cls[NC * CSTR];

    const int tid  = threadIdx.x;
    const int row0 = blockIdx.x * ROWS;
    const bool active = tid < NJT;

    float x = 0.0f;
    if (tid < NTAB) x = logits[(size_t)row0 * NC + tid];

    float4 tb[JPT];
    int ic[JPT] = {0, 0, 0, 0};
    if (active) {
        const int4 tv = reinterpret_cast<const int4*>(tids)[tid];
        ic[0] = tv.x; ic[1] = tv.y; ic[2] = tv.z; ic[3] = tv.w;
        #pragma unroll
        for (int k = 0; k < JPT; ++k)
            tb[k] = reinterpret_cast<const float4*>(tboxes)[tid * JPT + k];
    } else {
        #pragma unroll
        for (int k = 0; k < JPT; ++k) tb[k] = make_float4(0.f, 0.f, 0.f, 0.f);
    }

    if (tid < NTAB) {
        const int r = (tid >= NC) ? 1 : 0;
        const int c = tid - (r ? NC : 0);
        s_cls[c * CSTR + r] = focal_entry(x);
    }
    __syncthreads();

    if (!active) return;

    float cc0[JPT], cc1[JPT];
    #pragma unroll
    for (int k = 0; k < JPT; ++k) {
        const float* cp = s_cls + ic[k] * CSTR;
        cc0[k] = cp[0];
        cc1[k] = cp[1];
    }

    float* __restrict__ optr = out + (size_t)row0 * NT + tid * JPT;
    #pragma unroll
    for (int r = 0; r < ROWS; ++r) {
        const float4 pb = reinterpret_cast<const float4*>(boxes)[row0 + r];
        const float px0 = pb.x - 0.5f * pb.z, py0 = pb.y - 0.5f * pb.w;
        const float px1 = pb.x + 0.5f * pb.z, py1 = pb.y + 0.5f * pb.w;
        const float parea = pb.z * pb.w;

        float rv[JPT];
        #pragma unroll
        for (int k = 0; k < JPT; ++k) {
            const float4 t = tb[k];
            const float hw = 0.5f * t.z, hh = 0.5f * t.w;
            const float tx0 = t.x - hw, tx1 = t.x + hw;
            const float ty0 = t.y - hh, ty1 = t.y + hh;
            const float tarea = t.z * t.w;
            const float l1 = (fabsf(pb.x - t.x) + fabsf(pb.y - t.y))
                           + (fabsf(pb.z - t.z) + fabsf(pb.w - t.w));
            const float iwr = fminf(px1, tx1) - fmaxf(px0, tx0);
            const float ihr = fminf(py1, ty1) - fmaxf(py0, ty0);
            const float inter = fmaxf(iwr, 0.0f) * fmaxf(ihr, 0.0f);
            const float uni = (parea + tarea) - inter;
            const float cw = (pb.z + t.z) - iwr;
            const float ch = (pb.w + t.w) - ihr;
            const float carea = cw * ch;
            const float num  = fmaf(inter, carea, uni * uni);
            const float rcpd = __builtin_amdgcn_rcpf(uni * carea);
            const float ctab = (r == 0) ? cc0[k] : cc1[k];
            const float base = fmaf(COST_BBOX, l1, ctab);
            rv[k] = fmaf(-2.0f * num, rcpd, base);
        }
        vfloat4 v;
        v.x = rv[0]; v.y = rv[1]; v.z = rv[2]; v.w = rv[3];
        __builtin_nontemporal_store(v, reinterpret_cast<vfloat4*>(optr));
        optr += NT;
    }
}

// ----------------------------- generic fallback -----------------------------
constexpr int GROWS = 8;
__global__ __launch_bounds__(THREADS) void matcher_kernel_g(
    const float* __restrict__ logits, const float* __restrict__ boxes,
    const int* __restrict__ tids, const float* __restrict__ tboxes,
    float* __restrict__ out, int BN, int NC, int NT)
{
    extern __shared__ float s_cls_g[];
    const int tid  = threadIdx.x;
    const int row0 = blockIdx.x * GROWS;
    const int nrows = (BN - row0 < GROWS) ? (BN - row0) : GROWS;

    for (int t = tid; t < nrows * NC; t += THREADS) {
        const int r = t / NC, c = t - r * NC;
        const float x = logits[(size_t)(row0 + r) * NC + c];
        const float p  = 1.0f / (1.0f + expf(-x));
        const float om = 1.0f - p;
        const float neg = (1.0f - ALPHA_F) * p * p * (-logf(om + EPS_F));
        const float pos = ALPHA_F * om * om        * (-logf(p + EPS_F));
        s_cls_g[r * NC + c] = pos - neg;
    }
    __syncthreads();

    for (int r = 0; r < nrows; ++r) {
        const int row = row0 + r;
        const float4 pb = reinterpret_cast<const float4*>(boxes)[row];
        const float px0 = pb.x - 0.5f * pb.z, py0 = pb.y - 0.5f * pb.w;
        const float px1 = pb.x + 0.5f * pb.z, py1 = pb.y + 0.5f * pb.w;
        const float parea = pb.z * pb.w;
        for (int j = tid; j < NT; j += THREADS) {
            const float4 b = reinterpret_cast<const float4*>(tboxes)[j];
            const float bx0 = b.x - 0.5f * b.z, by0 = b.y - 0.5f * b.w;
            const float bx1 = b.x + 0.5f * b.z, by1 = b.y + 0.5f * b.w;
            const float l1 = fabsf(pb.x - b.x) + fabsf(pb.y - b.y)
                           + fabsf(pb.z - b.z) + fabsf(pb.w - b.w);
            const float iw = fmaxf(fminf(px1, bx1) - fmaxf(px0, bx0), 0.0f);
            const float ih = fmaxf(fminf(py1, by1) - fmaxf(py0, by0), 0.0f);
            const float inter = iw * ih;
            const float uni = parea + b.z * b.w - inter;
            const float iou = inter / uni;
            const float cw = fmaxf(px1, bx1) - fminf(px0, bx0);
            const float ch = fmaxf(py1, by1) - fminf(py0, by0);
            const float carea = cw * ch;
            const float giou = iou - (carea - uni) / carea;
            const float ccls = s_cls_g[r * NC + tids[j]];
            out[(size_t)row * NT + j] = COST_BBOX * l1 + COST_CLS * ccls - COST_GIOU * giou;
        }
        __syncthreads();
    }
}

extern "C" void kernel_launch(void* const* d_in, const int* in_sizes, int n_in,
                              void* d_out, int out_size, void* d_ws, size_t ws_size,
                              hipStream_t stream) {
    const float* logits = (const float*)d_in[0];
    const float* boxes  = (const float*)d_in[1];
    const int*   tids   = (const int*)d_in[2];
    const float* tboxes = (const float*)d_in[3];
    float* out = (float*)d_out;

    const int BN = in_sizes[1] / 4;       // 14400
    const int NC = in_sizes[0] / BN;      // 91
    const int NT = in_sizes[2];           // 960

    if (NC == 91 && NT == 960 && BN % 2 == 0) {
        const size_t tab_bytes = (size_t)BN * 96 * sizeof(float);
        if (ws_size >= tab_bytes) {
            float* tab = (float*)d_ws;
            const int total = BN * NC;                     // 1,310,400
            const int g1 = (total + THREADS - 1) / THREADS;
            focal_table_kernel<91, 96><<<g1, THREADS, 0, stream>>>(logits, tab, total);
            matcher_k2<91, 960><<<BN / 2, THREADS, 0, stream>>>(
                tab, boxes, tids, tboxes, out);
        } else {
            matcher_kernel_s<91, 960><<<BN / 2, THREADS, 0, stream>>>(
                logits, boxes, tids, tboxes, out);
        }
    } else {
        const int grid = (BN + GROWS - 1) / GROWS;
        const size_t shmem = (size_t)GROWS * NC * sizeof(float);
        matcher_kernel_g<<<grid, THREADS, shmem, stream>>>(
            logits, boxes, tids, tboxes, out, BN, NC, NT);
    }
}

// Round 12
// 21.339 us; speedup vs baseline: 1.4102x; 1.4102x over previous
//
#include <hip/hip_runtime.h>
#include <math.h>

// HungarianMatcher cost matrix:
//   C[i,j] = 5*L1(pred_box_i, tgt_box_j) + 2*focal(tgt class j) - 2*GIoU
// Shapes: pred_logits [BN,NC], pred_boxes [BN,4], tgt_ids [NT], tgt_bbox [NT,4]
// BN=16*900=14400, NC=91, NT=960. Output [BN,NT] fp32.
//
// R11: R9b (best, 21us) + branchless single-BB restructure. The FP body
// (needs only boxes, not the class table) runs BEFORE the barrier in the
// same basic block as the focal transcendental chain -> the scheduler
// interleaves the trans chain + cold logit load under ~300 VALU ops.
// All 256 threads execute everything (clamped indices, discarded results
// for lanes 240-255) so there are no divergent BB boundaries until the
// tiny predicated table-write / store tail.

#define ALPHA_F   0.25f
#define COST_CLS  2.0f
#define COST_BBOX 5.0f
#define COST_GIOU 2.0f
#define EPS_F     1e-8f

constexpr int THREADS = 256;

typedef float vfloat4 __attribute__((ext_vector_type(4)));

__device__ __forceinline__ float focal_entry(float x) {
    const float p  = 1.0f / (1.0f + __expf(-x));
    const float om = 1.0f - p;
    const float neg = (1.0f - ALPHA_F) * p * p * (-__logf(om + EPS_F));
    const float pos = ALPHA_F * om * om        * (-__logf(p  + EPS_F));
    return COST_CLS * (pos - neg) + COST_GIOU;   // GIoU "+2" folded in
}

// ---------------------- specialized kernel (ROWS = 2) -----------------------
template<int NC, int NT>
__global__ __launch_bounds__(THREADS) void matcher_kernel_s(
    const float* __restrict__ logits,   // [BN, NC]
    const float* __restrict__ boxes,    // [BN, 4] cxcywh
    const int*   __restrict__ tids,     // [NT]
    const float* __restrict__ tboxes,   // [NT, 4] cxcywh
    float*       __restrict__ out)      // [BN, NT]
{
    constexpr int ROWS = 2;
    constexpr int JPT  = 4;                   // contiguous targets per thread
    constexpr int NJT  = NT / JPT;            // 240 active threads
    constexpr int NTAB = ROWS * NC;           // 182 table entries (<= THREADS)
    constexpr int CSTR = 3;                   // class stride (coprime with 32)

    __shared__ float s_cls[NC * CSTR];        // ~1.1 KB

    const int tid  = threadIdx.x;
    const int row0 = blockIdx.x * ROWS;

    // ---- clamped indices: every thread does full work, no divergent BBs ----
    const int jb = (tid < NJT)  ? tid : (NJT - 1);
    const int tt = (tid < NTAB) ? tid : (NTAB - 1);

    // ---- issue all loads up front ----
    const float x = logits[(size_t)row0 * NC + tt];          // cold (HBM)
    const int4 tv = reinterpret_cast<const int4*>(tids)[jb]; // L1/L2 hot
    float4 tb[JPT];
    #pragma unroll
    for (int k = 0; k < JPT; ++k)
        tb[k] = reinterpret_cast<const float4*>(tboxes)[jb * JPT + k];
    const float4 pb0 = reinterpret_cast<const float4*>(boxes)[row0];     // scalar
    const float4 pb1 = reinterpret_cast<const float4*>(boxes)[row0 + 1]; // scalar

    // ---- FP body for both rows, pure VALU, runs while logit load/trans
    //      chain are in flight (same BB -> scheduler interleaves) ----
    float rv0[JPT], rv1[JPT];
    #pragma unroll
    for (int r = 0; r < ROWS; ++r) {
        const float4 pb = (r == 0) ? pb0 : pb1;
        const float px0 = pb.x - 0.5f * pb.z, py0 = pb.y - 0.5f * pb.w;
        const float px1 = pb.x + 0.5f * pb.z, py1 = pb.y + 0.5f * pb.w;
        const float parea = pb.z * pb.w;
        #pragma unroll
        for (int k = 0; k < JPT; ++k) {
            const float4 t = tb[k];
            const float hw = 0.5f * t.z, hh = 0.5f * t.w;
            const float tx0 = t.x - hw, tx1 = t.x + hw;
            const float ty0 = t.y - hh, ty1 = t.y + hh;
            const float tarea = t.z * t.w;
            // L1 in cxcywh space (abs folds into VOP3 src modifiers)
            const float l1 = (fabsf(pb.x - t.x) + fabsf(pb.y - t.y))
                           + (fabsf(pb.z - t.z) + fabsf(pb.w - t.w));
            // raw intersection extents (feed enclosing box too)
            const float iwr = fminf(px1, tx1) - fmaxf(px0, tx0);
            const float ihr = fminf(py1, ty1) - fmaxf(py0, ty0);
            const float inter = fmaxf(iwr, 0.0f) * fmaxf(ihr, 0.0f);
            const float uni = (parea + tarea) - inter;
            // enclosing box via identity: cw = pw + tw - iwr
            const float cw = (pb.z + t.z) - iwr;
            const float ch = (pb.w + t.w) - ihr;
            const float carea = cw * ch;
            // partial C (class cost added after the barrier):
            //   5*l1 - 2*(inter*carea + uni^2)/(uni*carea)
            const float num  = fmaf(inter, carea, uni * uni);
            const float rcpd = __builtin_amdgcn_rcpf(uni * carea);
            const float base = COST_BBOX * l1;
            const float v = fmaf(-2.0f * num, rcpd, base);
            if (r == 0) rv0[k] = v; else rv1[k] = v;
        }
    }

    // ---- focal chain (interleaved by scheduler into the body above) ----
    const float fe = focal_entry(x);
    if (tid < NTAB) {
        const int r = (tid >= NC) ? 1 : 0;
        const int c = tid - (r ? NC : 0);
        s_cls[c * CSTR + r] = fe;
    }
    __syncthreads();   // the only barrier; body is already done

    if (tid >= NJT) return;

    // ---- tiny tail: 8 LDS gathers + 8 adds + 2 NT stores ----
    const int ic[JPT] = {tv.x, tv.y, tv.z, tv.w};
    float cc0[JPT], cc1[JPT];
    #pragma unroll
    for (int k = 0; k < JPT; ++k) {
        const float* cp = s_cls + ic[k] * CSTR;
        cc0[k] = cp[0];
        cc1[k] = cp[1];
    }

    float* __restrict__ optr = out + (size_t)row0 * NT + tid * JPT;
    vfloat4 v0, v1;
    v0.x = rv0[0] + cc0[0]; v0.y = rv0[1] + cc0[1];
    v0.z = rv0[2] + cc0[2]; v0.w = rv0[3] + cc0[3];
    v1.x = rv1[0] + cc1[0]; v1.y = rv1[1] + cc1[1];
    v1.z = rv1[2] + cc1[2]; v1.w = rv1[3] + cc1[3];
    __builtin_nontemporal_store(v0, reinterpret_cast<vfloat4*>(optr));
    __builtin_nontemporal_store(v1, reinterpret_cast<vfloat4*>(optr + NT));
}

// ----------------------------- generic fallback -----------------------------
constexpr int GROWS = 8;
__global__ __launch_bounds__(THREADS) void matcher_kernel_g(
    const float* __restrict__ logits, const float* __restrict__ boxes,
    const int* __restrict__ tids, const float* __restrict__ tboxes,
    float* __restrict__ out, int BN, int NC, int NT)
{
    extern __shared__ float s_cls_g[];
    const int tid  = threadIdx.x;
    const int row0 = blockIdx.x * GROWS;
    const int nrows = (BN - row0 < GROWS) ? (BN - row0) : GROWS;

    for (int t = tid; t < nrows * NC; t += THREADS) {
        const int r = t / NC, c = t - r * NC;
        const float x = logits[(size_t)(row0 + r) * NC + c];
        const float p  = 1.0f / (1.0f + expf(-x));
        const float om = 1.0f - p;
        const float neg = (1.0f - ALPHA_F) * p * p * (-logf(om + EPS_F));
        const float pos = ALPHA_F * om * om        * (-logf(p + EPS_F));
        s_cls_g[r * NC + c] = pos - neg;
    }
    __syncthreads();

    for (int r = 0; r < nrows; ++r) {
        const int row = row0 + r;
        const float4 pb = reinterpret_cast<const float4*>(boxes)[row];
        const float px0 = pb.x - 0.5f * pb.z, py0 = pb.y - 0.5f * pb.w;
        const float px1 = pb.x + 0.5f * pb.z, py1 = pb.y + 0.5f * pb.w;
        const float parea = pb.z * pb.w;
        for (int j = tid; j < NT; j += THREADS) {
            const float4 b = reinterpret_cast<const float4*>(tboxes)[j];
            const float bx0 = b.x - 0.5f * b.z, by0 = b.y - 0.5f * b.w;
            const float bx1 = b.x + 0.5f * b.z, by1 = b.y + 0.5f * b.w;
            const float l1 = fabsf(pb.x - b.x) + fabsf(pb.y - b.y)
                           + fabsf(pb.z - b.z) + fabsf(pb.w - b.w);
            const float iw = fmaxf(fminf(px1, bx1) - fmaxf(px0, bx0), 0.0f);
            const float ih = fmaxf(fminf(py1, by1) - fmaxf(py0, by0), 0.0f);
            const float inter = iw * ih;
            const float uni = parea + b.z * b.w - inter;
            const float iou = inter / uni;
            const float cw = fmaxf(px1, bx1) - fminf(px0, bx0);
            const float ch = fmaxf(py1, by1) - fminf(py0, by0);
            const float carea = cw * ch;
            const float giou = iou - (carea - uni) / carea;
            const float ccls = s_cls_g[r * NC + tids[j]];
            out[(size_t)row * NT + j] = COST_BBOX * l1 + COST_CLS * ccls - COST_GIOU * giou;
        }
        __syncthreads();
    }
}

extern "C" void kernel_launch(void* const* d_in, const int* in_sizes, int n_in,
                              void* d_out, int out_size, void* d_ws, size_t ws_size,
                              hipStream_t stream) {
    const float* logits = (const float*)d_in[0];
    const float* boxes  = (const float*)d_in[1];
    const int*   tids   = (const int*)d_in[2];
    const float* tboxes = (const float*)d_in[3];
    float* out = (float*)d_out;

    const int BN = in_sizes[1] / 4;       // 14400
    const int NC = in_sizes[0] / BN;      // 91
    const int NT = in_sizes[2];           // 960

    if (NC == 91 && NT == 960 && BN % 2 == 0) {
        matcher_kernel_s<91, 960><<<BN / 2, THREADS, 0, stream>>>(
            logits, boxes, tids, tboxes, out);
    } else {
        const int grid = (BN + GROWS - 1) / GROWS;
        const size_t shmem = (size_t)GROWS * NC * sizeof(float);
        matcher_kernel_g<<<grid, THREADS, shmem, stream>>>(
            logits, boxes, tids, tboxes, out, BN, NC, NT);
    }
}